// Round 1
// baseline (309.850 us; speedup 1.0000x reference)
//
#include <hip/hip_runtime.h>
#include <stdint.h>

#define B_DIM 4
#define L_DIM 512
#define D_DIM 768
#define S_DIM 4096
#define DFF_DIM 3072
#define M_DIM (B_DIM * S_DIM)   // 16384

typedef unsigned short ushort_t;
typedef __attribute__((ext_vector_type(8))) short short8;
typedef __attribute__((ext_vector_type(4))) float floatx4;

// round-to-nearest-even fp32 -> bf16 bits
__device__ __forceinline__ ushort_t f2bf(float x) {
  unsigned int u = __float_as_uint(x);
  u += 0x7FFFu + ((u >> 16) & 1u);
  return (ushort_t)(u >> 16);
}

// async 16B global->LDS (wave-uniform base + lane*16 dest required)
__device__ __forceinline__ void load_lds16(const ushort_t* g, ushort_t* lds) {
  __builtin_amdgcn_global_load_lds(
      (const __attribute__((address_space(1))) unsigned int*)g,
      (__attribute__((address_space(3))) unsigned int*)lds, 16, 0, 0);
}

// raw barrier (no vmcnt drain) + compiler memory fences so LDS/global ops
// cannot be moved across phase boundaries by the compiler
#define BARRIER()                              \
  do {                                         \
    asm volatile("" ::: "memory");             \
    __builtin_amdgcn_s_barrier();              \
    asm volatile("" ::: "memory");             \
  } while (0)

// ---------------------------------------------------------------------------
// Fused prep: W1 transpose | W2 transpose | span gather+mean, one launch.
// ---------------------------------------------------------------------------
__device__ __forceinline__ void transpose_body(const float* __restrict__ in,
                                               ushort_t* __restrict__ out,
                                               int K, int N, int kb, int nb) {
  __shared__ float tile[32][33];
  const int k0 = kb * 32;
  const int n0 = nb * 32;
  const int tx = threadIdx.x & 31;
  const int ty = threadIdx.x >> 5;  // 0..7
#pragma unroll
  for (int r = 0; r < 32; r += 8)
    tile[ty + r][tx] = in[(long)(k0 + ty + r) * N + n0 + tx];
  __syncthreads();
#pragma unroll
  for (int r = 0; r < 32; r += 8)
    out[(long)(n0 + ty + r) * K + k0 + tx] = f2bf(tile[tx][ty + r]);
}

__device__ __forceinline__ void span_body(const float* __restrict__ h,
                                          const int* __restrict__ span_idx,
                                          ushort_t* __restrict__ A, int blk) {
  const int wave = threadIdx.x >> 6;
  const int lane = threadIdx.x & 63;
  const int span = blk * 4 + wave;  // 0..M-1
  const int b = span >> 12;         // span / S_DIM
  const int start = span_idx[span * 2 + 0];
  const int end   = span_idx[span * 2 + 1];
  const float inv = 1.0f / (float)(end - start + 1);
  const float* hb = h + ((long)b * L_DIM + start) * D_DIM + lane;
  float a[12];
#pragma unroll
  for (int c = 0; c < 12; ++c) a[c] = 0.0f;
  for (int p = start; p <= end; ++p) {
#pragma unroll
    for (int c = 0; c < 12; ++c) a[c] += hb[c * 64];
    hb += D_DIM;
  }
  ushort_t* o = A + (long)span * D_DIM + lane;
#pragma unroll
  for (int c = 0; c < 12; ++c) o[c * 64] = f2bf(a[c] * inv);
}

__global__ __launch_bounds__(256)
void prep(const float* __restrict__ W1, ushort_t* __restrict__ W1T,
          const float* __restrict__ W2, ushort_t* __restrict__ W2T,
          const float* __restrict__ h, const int* __restrict__ span_idx,
          ushort_t* __restrict__ A) {
  const int blk = blockIdx.x;
  if (blk < 2304) {
    transpose_body(W1, W1T, D_DIM, DFF_DIM, blk % 24, blk / 24);
  } else if (blk < 4608) {
    const int b = blk - 2304;
    transpose_body(W2, W2T, DFF_DIM, D_DIM, b % 96, b / 96);
  } else {
    span_body(h, span_idx, A, blk - 4608);
  }
}

// ---------------------------------------------------------------------------
// 256x256 / BK=64 / 8-wave phase-interleaved bf16 GEMM (T2+T3+T4+T5):
//   C[M][N] = A[M][K] * Bt[N][K]^T (+bias epilogue)
// - LDS XOR-8 swizzle: LDS slot (row, c') holds global k-chunk c'^(row&7).
//   Staging pre-swizzles the GLOBAL source (load_lds dest stays linear);
//   ds_read applies the same XOR -> conflict-free b128 reads.
// - Phase schedule per K-tile group k (buf cur = k&1):
//     P0: stage HI(k+1)->nxt | ds A0-3,B0-1 | BAR | MFMA q0 | BAR
//     P1:                      ds B2-3      | BAR | MFMA q1 | BAR
//     P2:                      ds A4-7      | BAR | MFMA q2 | BAR
//     P3: stage LO(k+2)->cur | MFMA q3 | s_waitcnt vmcnt(4) | BAR
//   vmcnt never drains to 0 in steady state: tile k+1's 8 loads retire at
//   P3 while tile k+2's 4 freshest stay in flight (3-4 phases of cover).
// MODE 0: out = relu(acc + bias[col]) -> bf16   (GEMM1 -> Hmid)
// MODE 1: out = acc + bias[col]       -> fp32   (GEMM2 -> final)
// ---------------------------------------------------------------------------
template <int MODE>
__global__ __launch_bounds__(512, 2)
void gemm256(const ushort_t* __restrict__ A, const ushort_t* __restrict__ Bt,
             const float* __restrict__ bias, void* __restrict__ Cv,
             int M, int N, int K) {
  __shared__ ushort_t As[2][256 * 64];
  __shared__ ushort_t Bs[2][256 * 64];

  const int tid  = threadIdx.x;
  const int lane = tid & 63;
  const int l16  = lane & 15;
  const int quad = lane >> 4;
  const int wave = tid >> 6;
  const int wr   = wave >> 2;  // 0..1 (M half)
  const int wc   = wave & 3;   // 0..3 (N quarter)

  const int bm = blockIdx.x;
  const int bn = blockIdx.y;

  // staging: linear seg s (16B) = LDS row s>>3, slot s&7; global chunk = slot^(row&7)
  const int srow   = tid >> 3;                 // 0..63
  const int schunk = (tid & 7) ^ (srow & 7);
  const ushort_t* gA = A  + (long)(bm * 256 + srow) * K + schunk * 8;
  const ushort_t* gB = Bt + (long)(bn * 256 + srow) * K + schunk * 8;
  const long rK64 = (long)K * 64;              // 64-row stride (chunk perm repeats mod 8)
  ushort_t* lA = &As[0][0] + tid * 8;
  ushort_t* lB = &Bs[0][0] + tid * 8;

  auto STAGE_LO = [&](int buf, int kt) {  // tile rows 0..127 of A and B
    const ushort_t* ga = gA + (long)kt * 64;
    const ushort_t* gb = gB + (long)kt * 64;
    ushort_t* la = lA + buf * (256 * 64);
    ushort_t* lb = lB + buf * (256 * 64);
    load_lds16(ga,        la);
    load_lds16(ga + rK64, la + 4096);
    load_lds16(gb,        lb);
    load_lds16(gb + rK64, lb + 4096);
  };
  auto STAGE_HI = [&](int buf, int kt) {  // tile rows 128..255
    const ushort_t* ga = gA + (long)kt * 64 + 2 * rK64;
    const ushort_t* gb = gB + (long)kt * 64 + 2 * rK64;
    ushort_t* la = lA + buf * (256 * 64);
    ushort_t* lb = lB + buf * (256 * 64);
    load_lds16(ga,        la + 8192);
    load_lds16(ga + rK64, la + 12288);
    load_lds16(gb,        lb + 8192);
    load_lds16(gb + rK64, lb + 12288);
  };

  // fragment reads: elem = row*64 + (chunk ^ (row&7))*8 ; row&7 == l16&7
  const int arow0 = (wr * 128 + l16) * 64;
  const int brow0 = (wc * 64 + l16) * 64;
  const int cx0 = ((quad)     ^ (l16 & 7)) << 3;  // kstep 0 chunk = quad
  const int cx1 = ((quad + 4) ^ (l16 & 7)) << 3;  // kstep 1 chunk = 4+quad

  floatx4 acc[8][4];
#pragma unroll
  for (int i = 0; i < 8; ++i)
#pragma unroll
    for (int j = 0; j < 4; ++j) acc[i][j] = (floatx4)0.0f;

  const int nk = K >> 6;

  // prologue: tile0 fully + LO(tile1); wait tile0 landed, LO(1) stays in flight
  STAGE_LO(0, 0);
  STAGE_HI(0, 0);
  if (nk > 1) {
    STAGE_LO(1, 1);
    asm volatile("s_waitcnt vmcnt(4)" ::: "memory");
  } else {
    asm volatile("s_waitcnt vmcnt(0)" ::: "memory");
  }
  BARRIER();

  short8 af[4][2], bf[4][2];

  for (int k = 0; k < nk; ++k) {
    const int cur = k & 1;
    const int nxt = cur ^ 1;
    const ushort_t* Ac = &As[cur][0];
    const ushort_t* Bc = &Bs[cur][0];

    // ---------------- P0: ds A rows0-3 + B cols0-1; stage HI(k+1) ----------
    if (k + 1 < nk) STAGE_HI(nxt, k + 1);
#pragma unroll
    for (int i = 0; i < 4; ++i) {
      af[i][0] = *(const short8*)(Ac + arow0 + i * 1024 + cx0);
      af[i][1] = *(const short8*)(Ac + arow0 + i * 1024 + cx1);
    }
#pragma unroll
    for (int j = 0; j < 2; ++j) {
      bf[j][0] = *(const short8*)(Bc + brow0 + j * 1024 + cx0);
      bf[j][1] = *(const short8*)(Bc + brow0 + j * 1024 + cx1);
    }
    BARRIER();
    asm volatile("s_waitcnt lgkmcnt(0)" ::: "memory");
    __builtin_amdgcn_sched_barrier(0);
    __builtin_amdgcn_s_setprio(1);
#pragma unroll
    for (int i = 0; i < 4; ++i)
#pragma unroll
      for (int j = 0; j < 2; ++j) {
        acc[i][j] = __builtin_amdgcn_mfma_f32_16x16x32_bf16(af[i][0], bf[j][0], acc[i][j], 0, 0, 0);
        acc[i][j] = __builtin_amdgcn_mfma_f32_16x16x32_bf16(af[i][1], bf[j][1], acc[i][j], 0, 0, 0);
      }
    __builtin_amdgcn_s_setprio(0);
    BARRIER();

    // ---------------- P1: ds B cols2-3 ------------------------------------
#pragma unroll
    for (int j = 0; j < 2; ++j) {
      bf[2 + j][0] = *(const short8*)(Bc + brow0 + (2 + j) * 1024 + cx0);
      bf[2 + j][1] = *(const short8*)(Bc + brow0 + (2 + j) * 1024 + cx1);
    }
    BARRIER();
    asm volatile("s_waitcnt lgkmcnt(0)" ::: "memory");
    __builtin_amdgcn_sched_barrier(0);
    __builtin_amdgcn_s_setprio(1);
#pragma unroll
    for (int i = 0; i < 4; ++i)
#pragma unroll
      for (int j = 0; j < 2; ++j) {
        acc[i][2 + j] = __builtin_amdgcn_mfma_f32_16x16x32_bf16(af[i][0], bf[2 + j][0], acc[i][2 + j], 0, 0, 0);
        acc[i][2 + j] = __builtin_amdgcn_mfma_f32_16x16x32_bf16(af[i][1], bf[2 + j][1], acc[i][2 + j], 0, 0, 0);
      }
    __builtin_amdgcn_s_setprio(0);
    BARRIER();

    // ---------------- P2: ds A rows4-7 ------------------------------------
#pragma unroll
    for (int i = 0; i < 4; ++i) {
      af[i][0] = *(const short8*)(Ac + arow0 + (4 + i) * 1024 + cx0);
      af[i][1] = *(const short8*)(Ac + arow0 + (4 + i) * 1024 + cx1);
    }
    BARRIER();
    asm volatile("s_waitcnt lgkmcnt(0)" ::: "memory");
    __builtin_amdgcn_sched_barrier(0);
    __builtin_amdgcn_s_setprio(1);
#pragma unroll
    for (int i = 0; i < 4; ++i)
#pragma unroll
      for (int j = 0; j < 2; ++j) {
        acc[4 + i][2 + j] = __builtin_amdgcn_mfma_f32_16x16x32_bf16(af[i][0], bf[2 + j][0], acc[4 + i][2 + j], 0, 0, 0);
        acc[4 + i][2 + j] = __builtin_amdgcn_mfma_f32_16x16x32_bf16(af[i][1], bf[2 + j][1], acc[4 + i][2 + j], 0, 0, 0);
      }
    __builtin_amdgcn_s_setprio(0);
    BARRIER();

    // ---------------- P3: stage LO(k+2) | MFMA q3 | counted vmcnt ----------
    if (k + 2 < nk) {
      STAGE_LO(cur, k + 2);  // buf cur's last reads finished at P2's barrier
      __builtin_amdgcn_s_setprio(1);
#pragma unroll
      for (int i = 0; i < 4; ++i)
#pragma unroll
        for (int j = 0; j < 2; ++j) {
          acc[4 + i][j] = __builtin_amdgcn_mfma_f32_16x16x32_bf16(af[i][0], bf[j][0], acc[4 + i][j], 0, 0, 0);
          acc[4 + i][j] = __builtin_amdgcn_mfma_f32_16x16x32_bf16(af[i][1], bf[j][1], acc[4 + i][j], 0, 0, 0);
        }
      __builtin_amdgcn_s_setprio(0);
      asm volatile("s_waitcnt vmcnt(4)" ::: "memory");  // tile k+1 landed; LO(k+2) in flight
    } else {
      __builtin_amdgcn_s_setprio(1);
#pragma unroll
      for (int i = 0; i < 4; ++i)
#pragma unroll
        for (int j = 0; j < 2; ++j) {
          acc[4 + i][j] = __builtin_amdgcn_mfma_f32_16x16x32_bf16(af[i][0], bf[j][0], acc[4 + i][j], 0, 0, 0);
          acc[4 + i][j] = __builtin_amdgcn_mfma_f32_16x16x32_bf16(af[i][1], bf[j][1], acc[4 + i][j], 0, 0, 0);
        }
      __builtin_amdgcn_s_setprio(0);
      asm volatile("s_waitcnt vmcnt(0)" ::: "memory");  // epilogue of the pipeline
    }
    BARRIER();
  }

  // epilogue: C/D layout col = l16, row = quad*4 + r
  const long rowbase = (long)bm * 256 + wr * 128 + quad * 4;
  const int  colbase = bn * 256 + wc * 64 + l16;
#pragma unroll
  for (int j = 0; j < 4; ++j) {
    const int col = colbase + j * 16;
    const float bv = bias[col];
#pragma unroll
    for (int i = 0; i < 8; ++i) {
      const long row0 = rowbase + i * 16;
#pragma unroll
      for (int r = 0; r < 4; ++r) {
        float v = acc[i][j][r] + bv;
        if (MODE == 0) {
          v = v > 0.0f ? v : 0.0f;
          ((ushort_t*)Cv)[(row0 + r) * N + col] = f2bf(v);
        } else {
          ((float*)Cv)[(row0 + r) * N + col] = v;
        }
      }
    }
  }
}

extern "C" void kernel_launch(void* const* d_in, const int* in_sizes, int n_in,
                              void* d_out, int out_size, void* d_ws, size_t ws_size,
                              hipStream_t stream) {
  const float* h        = (const float*)d_in[0];
  const int*   span_idx = (const int*)d_in[1];
  const float* W1       = (const float*)d_in[2];
  const float* b1       = (const float*)d_in[3];
  const float* W2       = (const float*)d_in[4];
  const float* b2       = (const float*)d_in[5];
  float* out = (float*)d_out;

  // workspace layout (bf16 elements): A | W1T | W2T | Hmid
  ushort_t* A   = (ushort_t*)d_ws;
  ushort_t* W1T = A + (size_t)M_DIM * D_DIM;
  ushort_t* W2T = W1T + (size_t)DFF_DIM * D_DIM;
  ushort_t* Hm  = W2T + (size_t)D_DIM * DFF_DIM;

  // fused prep: both weight transposes + span gather in one launch
  prep<<<2304 + 2304 + M_DIM / 4, 256, 0, stream>>>(W1, W1T, W2, W2T, h, span_idx, A);

  // GEMM1: A (M x D) * W1 (D x DFF) + b1, relu -> Hmid bf16 (M x DFF)
  gemm256<0><<<dim3(M_DIM / 256, DFF_DIM / 256), 512, 0, stream>>>(
      A, W1T, b1, Hm, M_DIM, DFF_DIM, D_DIM);

  // GEMM2: Hmid (M x DFF) * W2 (DFF x D) + b2 -> out fp32 (M x D)
  gemm256<1><<<dim3(M_DIM / 256, D_DIM / 256), 512, 0, stream>>>(
      Hm, W2T, b2, out, M_DIM, D_DIM, DFF_DIM);
}

// Round 2
// 309.193 us; speedup vs baseline: 1.0021x; 1.0021x over previous
//
#include <hip/hip_runtime.h>
#include <stdint.h>

#define B_DIM 4
#define L_DIM 512
#define D_DIM 768
#define S_DIM 4096
#define DFF_DIM 3072
#define M_DIM (B_DIM * S_DIM)   // 16384

typedef unsigned short ushort_t;
typedef __attribute__((ext_vector_type(8))) short short8;
typedef __attribute__((ext_vector_type(4))) float floatx4;

// round-to-nearest-even fp32 -> bf16 bits
__device__ __forceinline__ ushort_t f2bf(float x) {
  unsigned int u = __float_as_uint(x);
  u += 0x7FFFu + ((u >> 16) & 1u);
  return (ushort_t)(u >> 16);
}

// async 16B global->LDS (wave-uniform base + lane*16 dest required)
__device__ __forceinline__ void load_lds16(const ushort_t* g, ushort_t* lds) {
  __builtin_amdgcn_global_load_lds(
      (const __attribute__((address_space(1))) unsigned int*)g,
      (__attribute__((address_space(3))) unsigned int*)lds, 16, 0, 0);
}

// Phase barrier WITHOUT memory clobbers: sched_barrier(0) pins instruction
// motion at codegen; raw s_barrier adds no waitcnt. A "memory" clobber here
// would make the compiler drain vmcnt(0) (outstanding global_load_lds) at
// every fence -- exactly the stall this schedule exists to avoid.
#define BARRIER()                              \
  do {                                         \
    __builtin_amdgcn_sched_barrier(0);         \
    __builtin_amdgcn_s_barrier();              \
    __builtin_amdgcn_sched_barrier(0);         \
  } while (0)

#define WAIT_LGKM0()                           \
  do {                                         \
    asm volatile("s_waitcnt lgkmcnt(0)");      \
    __builtin_amdgcn_sched_barrier(0);         \
  } while (0)

#define WAIT_VM(n)                             \
  do {                                         \
    asm volatile("s_waitcnt vmcnt(" #n ")");   \
    __builtin_amdgcn_sched_barrier(0);         \
  } while (0)

// ---------------------------------------------------------------------------
// Fused prep: W1 transpose | W2 transpose | span gather+mean, one launch.
// ---------------------------------------------------------------------------
__device__ __forceinline__ void transpose_body(const float* __restrict__ in,
                                               ushort_t* __restrict__ out,
                                               int K, int N, int kb, int nb) {
  __shared__ float tile[32][33];
  const int k0 = kb * 32;
  const int n0 = nb * 32;
  const int tx = threadIdx.x & 31;
  const int ty = threadIdx.x >> 5;  // 0..7
#pragma unroll
  for (int r = 0; r < 32; r += 8)
    tile[ty + r][tx] = in[(long)(k0 + ty + r) * N + n0 + tx];
  __syncthreads();
#pragma unroll
  for (int r = 0; r < 32; r += 8)
    out[(long)(n0 + ty + r) * K + k0 + tx] = f2bf(tile[tx][ty + r]);
}

__device__ __forceinline__ void span_body(const float* __restrict__ h,
                                          const int* __restrict__ span_idx,
                                          ushort_t* __restrict__ A, int blk) {
  const int wave = threadIdx.x >> 6;
  const int lane = threadIdx.x & 63;
  const int span = blk * 4 + wave;  // 0..M-1
  const int b = span >> 12;         // span / S_DIM
  const int start = span_idx[span * 2 + 0];
  const int end   = span_idx[span * 2 + 1];
  const float inv = 1.0f / (float)(end - start + 1);
  const float* hb = h + ((long)b * L_DIM + start) * D_DIM + lane;
  float a[12];
#pragma unroll
  for (int c = 0; c < 12; ++c) a[c] = 0.0f;
  for (int p = start; p <= end; ++p) {
#pragma unroll
    for (int c = 0; c < 12; ++c) a[c] += hb[c * 64];
    hb += D_DIM;
  }
  ushort_t* o = A + (long)span * D_DIM + lane;
#pragma unroll
  for (int c = 0; c < 12; ++c) o[c * 64] = f2bf(a[c] * inv);
}

__global__ __launch_bounds__(256)
void prep(const float* __restrict__ W1, ushort_t* __restrict__ W1T,
          const float* __restrict__ W2, ushort_t* __restrict__ W2T,
          const float* __restrict__ h, const int* __restrict__ span_idx,
          ushort_t* __restrict__ A) {
  const int blk = blockIdx.x;
  if (blk < 2304) {
    transpose_body(W1, W1T, D_DIM, DFF_DIM, blk % 24, blk / 24);
  } else if (blk < 4608) {
    const int b = blk - 2304;
    transpose_body(W2, W2T, DFF_DIM, D_DIM, b % 96, b / 96);
  } else {
    span_body(h, span_idx, A, blk - 4608);
  }
}

// ---------------------------------------------------------------------------
// 256x256 / BK=64 / 8-wave phase-interleaved bf16 GEMM (T2+T3+T4+T5):
//   C[M][N] = A[M][K] * Bt[N][K]^T (+bias epilogue)
// - LDS XOR-8 swizzle: LDS slot (row, c') holds global k-chunk c'^(row&7).
//   Staging pre-swizzles the GLOBAL source (load_lds dest stays linear);
//   ds_read applies the same XOR -> conflict-free b128 reads (verified: 0
//   SQ_LDS_BANK_CONFLICT in round 1).
// - Phase schedule per K-tile group k (buf cur = k&1):
//     P0: stage HI(k+1)->nxt | ds A0-3,B0-1 | BAR | lgkm0 | MFMA q0 | BAR
//     P1:                      ds B2-3      | BAR | lgkm0 | MFMA q1 | BAR
//     P2:                      ds A4-7      | BAR | lgkm0 | MFMA q2 | BAR
//     P3: stage LO(k+2)->cur | MFMA q3 | s_waitcnt vmcnt(4) | BAR
//   vmcnt never drains to 0 in steady state: at P3's wait, tile k+1's 8
//   loads have retired while LO(k+2)'s 4 stay in flight.
// MODE 0: out = relu(acc + bias[col]) -> bf16   (GEMM1 -> Hmid)
// MODE 1: out = acc + bias[col]       -> fp32   (GEMM2 -> final)
// ---------------------------------------------------------------------------
template <int MODE>
__global__ __launch_bounds__(512, 2)
void gemm256(const ushort_t* __restrict__ A, const ushort_t* __restrict__ Bt,
             const float* __restrict__ bias, void* __restrict__ Cv,
             int M, int N, int K) {
  __shared__ ushort_t As[2][256 * 64];
  __shared__ ushort_t Bs[2][256 * 64];

  const int tid  = threadIdx.x;
  const int lane = tid & 63;
  const int l16  = lane & 15;
  const int quad = lane >> 4;
  const int wave = tid >> 6;
  const int wr   = wave >> 2;  // 0..1 (M half)
  const int wc   = wave & 3;   // 0..3 (N quarter)

  const int bm = blockIdx.x;
  const int bn = blockIdx.y;

  // staging: linear seg s (16B) = LDS row s>>3, slot s&7; global chunk = slot^(row&7)
  const int srow   = tid >> 3;                 // 0..63
  const int schunk = (tid & 7) ^ (srow & 7);
  const ushort_t* gA = A  + (long)(bm * 256 + srow) * K + schunk * 8;
  const ushort_t* gB = Bt + (long)(bn * 256 + srow) * K + schunk * 8;
  const long rK64 = (long)K * 64;              // 64-row stride (chunk perm repeats mod 8)
  ushort_t* lA = &As[0][0] + tid * 8;
  ushort_t* lB = &Bs[0][0] + tid * 8;

  auto STAGE_LO = [&](int buf, int kt) {  // tile rows 0..127 of A and B
    const ushort_t* ga = gA + (long)kt * 64;
    const ushort_t* gb = gB + (long)kt * 64;
    ushort_t* la = lA + buf * (256 * 64);
    ushort_t* lb = lB + buf * (256 * 64);
    load_lds16(ga,        la);
    load_lds16(ga + rK64, la + 4096);
    load_lds16(gb,        lb);
    load_lds16(gb + rK64, lb + 4096);
  };
  auto STAGE_HI = [&](int buf, int kt) {  // tile rows 128..255
    const ushort_t* ga = gA + (long)kt * 64 + 2 * rK64;
    const ushort_t* gb = gB + (long)kt * 64 + 2 * rK64;
    ushort_t* la = lA + buf * (256 * 64);
    ushort_t* lb = lB + buf * (256 * 64);
    load_lds16(ga,        la + 8192);
    load_lds16(ga + rK64, la + 12288);
    load_lds16(gb,        lb + 8192);
    load_lds16(gb + rK64, lb + 12288);
  };

  // fragment reads: elem = row*64 + (chunk ^ (row&7))*8 ; row&7 == l16&7
  const int arow0 = (wr * 128 + l16) * 64;
  const int brow0 = (wc * 64 + l16) * 64;
  const int cx0 = ((quad)     ^ (l16 & 7)) << 3;  // kstep 0 chunk = quad
  const int cx1 = ((quad + 4) ^ (l16 & 7)) << 3;  // kstep 1 chunk = 4+quad

  floatx4 acc[8][4];
#pragma unroll
  for (int i = 0; i < 8; ++i)
#pragma unroll
    for (int j = 0; j < 4; ++j) acc[i][j] = (floatx4)0.0f;

  const int nk = K >> 6;

  // prologue: tile0 fully + LO(tile1); wait tile0 landed, LO(1) stays in flight
  STAGE_LO(0, 0);
  STAGE_HI(0, 0);
  if (nk > 1) {
    STAGE_LO(1, 1);
    WAIT_VM(4);
  } else {
    WAIT_VM(0);
  }
  BARRIER();

  short8 af[4][2], bf[4][2];

  for (int k = 0; k < nk; ++k) {
    const int cur = k & 1;
    const int nxt = cur ^ 1;
    const ushort_t* Ac = &As[cur][0];
    const ushort_t* Bc = &Bs[cur][0];

    // ---------------- P0: ds A rows0-3 + B cols0-1; stage HI(k+1) ----------
    if (k + 1 < nk) STAGE_HI(nxt, k + 1);
#pragma unroll
    for (int i = 0; i < 4; ++i) {
      af[i][0] = *(const short8*)(Ac + arow0 + i * 1024 + cx0);
      af[i][1] = *(const short8*)(Ac + arow0 + i * 1024 + cx1);
    }
#pragma unroll
    for (int j = 0; j < 2; ++j) {
      bf[j][0] = *(const short8*)(Bc + brow0 + j * 1024 + cx0);
      bf[j][1] = *(const short8*)(Bc + brow0 + j * 1024 + cx1);
    }
    BARRIER();
    WAIT_LGKM0();
    __builtin_amdgcn_s_setprio(1);
#pragma unroll
    for (int i = 0; i < 4; ++i)
#pragma unroll
      for (int j = 0; j < 2; ++j) {
        acc[i][j] = __builtin_amdgcn_mfma_f32_16x16x32_bf16(af[i][0], bf[j][0], acc[i][j], 0, 0, 0);
        acc[i][j] = __builtin_amdgcn_mfma_f32_16x16x32_bf16(af[i][1], bf[j][1], acc[i][j], 0, 0, 0);
      }
    __builtin_amdgcn_s_setprio(0);
    BARRIER();

    // ---------------- P1: ds B cols2-3 ------------------------------------
#pragma unroll
    for (int j = 0; j < 2; ++j) {
      bf[2 + j][0] = *(const short8*)(Bc + brow0 + (2 + j) * 1024 + cx0);
      bf[2 + j][1] = *(const short8*)(Bc + brow0 + (2 + j) * 1024 + cx1);
    }
    BARRIER();
    WAIT_LGKM0();
    __builtin_amdgcn_s_setprio(1);
#pragma unroll
    for (int i = 0; i < 4; ++i)
#pragma unroll
      for (int j = 0; j < 2; ++j) {
        acc[i][2 + j] = __builtin_amdgcn_mfma_f32_16x16x32_bf16(af[i][0], bf[2 + j][0], acc[i][2 + j], 0, 0, 0);
        acc[i][2 + j] = __builtin_amdgcn_mfma_f32_16x16x32_bf16(af[i][1], bf[2 + j][1], acc[i][2 + j], 0, 0, 0);
      }
    __builtin_amdgcn_s_setprio(0);
    BARRIER();

    // ---------------- P2: ds A rows4-7 ------------------------------------
#pragma unroll
    for (int i = 0; i < 4; ++i) {
      af[i][0] = *(const short8*)(Ac + arow0 + (4 + i) * 1024 + cx0);
      af[i][1] = *(const short8*)(Ac + arow0 + (4 + i) * 1024 + cx1);
    }
    BARRIER();
    WAIT_LGKM0();
    __builtin_amdgcn_s_setprio(1);
#pragma unroll
    for (int i = 0; i < 4; ++i)
#pragma unroll
      for (int j = 0; j < 2; ++j) {
        acc[4 + i][2 + j] = __builtin_amdgcn_mfma_f32_16x16x32_bf16(af[i][0], bf[2 + j][0], acc[4 + i][2 + j], 0, 0, 0);
        acc[4 + i][2 + j] = __builtin_amdgcn_mfma_f32_16x16x32_bf16(af[i][1], bf[2 + j][1], acc[4 + i][2 + j], 0, 0, 0);
      }
    __builtin_amdgcn_s_setprio(0);
    BARRIER();

    // ---------------- P3: stage LO(k+2) | MFMA q3 | counted vmcnt ----------
    if (k + 2 < nk) {
      STAGE_LO(cur, k + 2);  // buf cur's last reads finished at P2's barrier
      __builtin_amdgcn_s_setprio(1);
#pragma unroll
      for (int i = 0; i < 4; ++i)
#pragma unroll
        for (int j = 0; j < 2; ++j) {
          acc[4 + i][j] = __builtin_amdgcn_mfma_f32_16x16x32_bf16(af[i][0], bf[j][0], acc[4 + i][j], 0, 0, 0);
          acc[4 + i][j] = __builtin_amdgcn_mfma_f32_16x16x32_bf16(af[i][1], bf[j][1], acc[4 + i][j], 0, 0, 0);
        }
      __builtin_amdgcn_s_setprio(0);
      WAIT_VM(4);  // tile k+1 landed; LO(k+2)'s 4 stay in flight
    } else {
      __builtin_amdgcn_s_setprio(1);
#pragma unroll
      for (int i = 0; i < 4; ++i)
#pragma unroll
        for (int j = 0; j < 2; ++j) {
          acc[4 + i][j] = __builtin_amdgcn_mfma_f32_16x16x32_bf16(af[i][0], bf[j][0], acc[4 + i][j], 0, 0, 0);
          acc[4 + i][j] = __builtin_amdgcn_mfma_f32_16x16x32_bf16(af[i][1], bf[j][1], acc[4 + i][j], 0, 0, 0);
        }
      __builtin_amdgcn_s_setprio(0);
      WAIT_VM(0);  // pipeline drain on last iter
    }
    BARRIER();
  }

  // epilogue: C/D layout col = l16, row = quad*4 + r
  const long rowbase = (long)bm * 256 + wr * 128 + quad * 4;
  const int  colbase = bn * 256 + wc * 64 + l16;
#pragma unroll
  for (int j = 0; j < 4; ++j) {
    const int col = colbase + j * 16;
    const float bv = bias[col];
#pragma unroll
    for (int i = 0; i < 8; ++i) {
      const long row0 = rowbase + i * 16;
#pragma unroll
      for (int r = 0; r < 4; ++r) {
        float v = acc[i][j][r] + bv;
        if (MODE == 0) {
          v = v > 0.0f ? v : 0.0f;
          ((ushort_t*)Cv)[(row0 + r) * N + col] = f2bf(v);
        } else {
          ((float*)Cv)[(row0 + r) * N + col] = v;
        }
      }
    }
  }
}

extern "C" void kernel_launch(void* const* d_in, const int* in_sizes, int n_in,
                              void* d_out, int out_size, void* d_ws, size_t ws_size,
                              hipStream_t stream) {
  const float* h        = (const float*)d_in[0];
  const int*   span_idx = (const int*)d_in[1];
  const float* W1       = (const float*)d_in[2];
  const float* b1       = (const float*)d_in[3];
  const float* W2       = (const float*)d_in[4];
  const float* b2       = (const float*)d_in[5];
  float* out = (float*)d_out;

  // workspace layout (bf16 elements): A | W1T | W2T | Hmid
  ushort_t* A   = (ushort_t*)d_ws;
  ushort_t* W1T = A + (size_t)M_DIM * D_DIM;
  ushort_t* W2T = W1T + (size_t)DFF_DIM * D_DIM;
  ushort_t* Hm  = W2T + (size_t)D_DIM * DFF_DIM;

  // fused prep: both weight transposes + span gather in one launch
  prep<<<2304 + 2304 + M_DIM / 4, 256, 0, stream>>>(W1, W1T, W2, W2T, h, span_idx, A);

  // GEMM1: A (M x D) * W1 (D x DFF) + b1, relu -> Hmid bf16 (M x DFF)
  gemm256<0><<<dim3(M_DIM / 256, DFF_DIM / 256), 512, 0, stream>>>(
      A, W1T, b1, Hm, M_DIM, DFF_DIM, D_DIM);

  // GEMM2: Hmid (M x DFF) * W2 (DFF x D) + b2 -> out fp32 (M x D)
  gemm256<1><<<dim3(M_DIM / 256, D_DIM / 256), 512, 0, stream>>>(
      Hm, W2T, b2, out, M_DIM, D_DIM, DFF_DIM);
}

// Round 3
// 309.150 us; speedup vs baseline: 1.0023x; 1.0001x over previous
//
#include <hip/hip_runtime.h>
#include <stdint.h>

#define B_DIM 4
#define L_DIM 512
#define D_DIM 768
#define S_DIM 4096
#define DFF_DIM 3072
#define M_DIM (B_DIM * S_DIM)   // 16384

typedef unsigned short ushort_t;
typedef __attribute__((ext_vector_type(8))) short short8;
typedef __attribute__((ext_vector_type(4))) short short4v;
typedef __attribute__((ext_vector_type(4))) float floatx4;

// round-to-nearest-even fp32 -> bf16 bits
__device__ __forceinline__ ushort_t f2bf(float x) {
  unsigned int u = __float_as_uint(x);
  u += 0x7FFFu + ((u >> 16) & 1u);
  return (ushort_t)(u >> 16);
}

// async 16B global->LDS (wave-uniform base + lane*16 dest required)
__device__ __forceinline__ void load_lds16(const ushort_t* g, ushort_t* lds) {
  __builtin_amdgcn_global_load_lds(
      (const __attribute__((address_space(1))) unsigned int*)g,
      (__attribute__((address_space(3))) unsigned int*)lds, 16, 0, 0);
}

// Phase barrier without memory clobbers (raw s_barrier; no vmcnt drain).
#define BARRIER()                              \
  do {                                         \
    __builtin_amdgcn_sched_barrier(0);         \
    __builtin_amdgcn_s_barrier();              \
    __builtin_amdgcn_sched_barrier(0);         \
  } while (0)

#define WAIT_LGKM0()                           \
  do {                                         \
    asm volatile("s_waitcnt lgkmcnt(0)");      \
    __builtin_amdgcn_sched_barrier(0);         \
  } while (0)

#define WAIT_VM(n)                             \
  do {                                         \
    asm volatile("s_waitcnt vmcnt(" #n ")");   \
    __builtin_amdgcn_sched_barrier(0);         \
  } while (0)

// ---------------------------------------------------------------------------
// Fused prep: W1 transpose | W2 transpose | span gather+mean, one launch.
// Span gather vectorized: float4 loads (3 per row instead of 12 scalar),
// short4 bf16 stores (G13 -- hipcc does not auto-vectorize).
// ---------------------------------------------------------------------------
__device__ __forceinline__ void transpose_body(const float* __restrict__ in,
                                               ushort_t* __restrict__ out,
                                               int K, int N, int kb, int nb) {
  __shared__ float tile[32][33];
  const int k0 = kb * 32;
  const int n0 = nb * 32;
  const int tx = threadIdx.x & 31;
  const int ty = threadIdx.x >> 5;  // 0..7
#pragma unroll
  for (int r = 0; r < 32; r += 8)
    tile[ty + r][tx] = in[(long)(k0 + ty + r) * N + n0 + tx];
  __syncthreads();
#pragma unroll
  for (int r = 0; r < 32; r += 8)
    out[(long)(n0 + ty + r) * K + k0 + tx] = f2bf(tile[tx][ty + r]);
}

__device__ __forceinline__ void span_body(const float* __restrict__ h,
                                          const int* __restrict__ span_idx,
                                          ushort_t* __restrict__ A, int blk) {
  const int wave = threadIdx.x >> 6;
  const int lane = threadIdx.x & 63;
  const int span = blk * 4 + wave;  // 0..M-1
  const int b = span >> 12;         // span / S_DIM
  const int start = span_idx[span * 2 + 0];
  const int end   = span_idx[span * 2 + 1];
  const float inv = 1.0f / (float)(end - start + 1);
  // lane handles cols {c*256 + lane*4 .. +3} for c = 0..2 (768 = 3*64*4)
  const floatx4* hb =
      (const floatx4*)(h + ((long)b * L_DIM + start) * D_DIM) + lane;
  floatx4 a[3];
#pragma unroll
  for (int c = 0; c < 3; ++c) a[c] = (floatx4)0.0f;
  for (int p = start; p <= end; ++p) {
#pragma unroll
    for (int c = 0; c < 3; ++c) a[c] += hb[c * 64];
    hb += 192;  // 768 floats / 4
  }
  short4v* o = (short4v*)(A + (long)span * D_DIM) + lane;
#pragma unroll
  for (int c = 0; c < 3; ++c) {
    short4v s;
#pragma unroll
    for (int e = 0; e < 4; ++e) s[e] = (short)f2bf(a[c][e] * inv);
    o[c * 64] = s;
  }
}

__global__ __launch_bounds__(256)
void prep(const float* __restrict__ W1, ushort_t* __restrict__ W1T,
          const float* __restrict__ W2, ushort_t* __restrict__ W2T,
          const float* __restrict__ h, const int* __restrict__ span_idx,
          ushort_t* __restrict__ A) {
  const int blk = blockIdx.x;
  if (blk < 2304) {
    transpose_body(W1, W1T, D_DIM, DFF_DIM, blk % 24, blk / 24);
  } else if (blk < 4608) {
    const int b = blk - 2304;
    transpose_body(W2, W2T, DFF_DIM, D_DIM, b % 96, b / 96);
  } else {
    span_body(h, span_idx, A, blk - 4608);
  }
}

// ---------------------------------------------------------------------------
// 256x256 / BK=64 / 8-wave phase-interleaved bf16 GEMM (T2+T3+T4+T5)
// with XCD-grouped block swizzle (T1):
//   1-D grid, id -> xcd = id&7, l = id>>3, bm = xcd*8 + (l&7), bn = l>>3.
//   Each XCD keeps a STABLE set of 8 A-panels (8 x 384KB = 3MB, fits its
//   4MiB L2) across all bn rounds; bn advances slowly so each B-panel is
//   fetched into an XCD's L2 once. Converts staging traffic from the
//   shared LLC path (~24 B/cy/CU cap) to L2 hits (~60 B/cy/CU).
//   Bijective: requires nbm % 8 == 0 (nbm = 64 for both GEMMs).
// MODE 0: out = relu(acc + bias[col]) -> bf16   (GEMM1 -> Hmid)
// MODE 1: out = acc + bias[col]       -> fp32   (GEMM2 -> final)
// ---------------------------------------------------------------------------
template <int MODE>
__global__ __launch_bounds__(512, 2)
void gemm256(const ushort_t* __restrict__ A, const ushort_t* __restrict__ Bt,
             const float* __restrict__ bias, void* __restrict__ Cv,
             int M, int N, int K) {
  __shared__ ushort_t As[2][256 * 64];
  __shared__ ushort_t Bs[2][256 * 64];

  const int tid  = threadIdx.x;
  const int lane = tid & 63;
  const int l16  = lane & 15;
  const int quad = lane >> 4;
  const int wave = tid >> 6;
  const int wr   = wave >> 2;  // 0..1 (M half)
  const int wc   = wave & 3;   // 0..3 (N quarter)

  // XCD-grouped swizzle (nbm = M/256 = 64, groups of 8 bm per XCD)
  const int id  = blockIdx.x;
  const int xcd = id & 7;
  const int l   = id >> 3;
  const int bm  = xcd * 8 + (l & 7);
  const int bn  = l >> 3;

  // staging: linear seg s (16B) = LDS row s>>3, slot s&7; global chunk = slot^(row&7)
  const int srow   = tid >> 3;                 // 0..63
  const int schunk = (tid & 7) ^ (srow & 7);
  const ushort_t* gA = A  + (long)(bm * 256 + srow) * K + schunk * 8;
  const ushort_t* gB = Bt + (long)(bn * 256 + srow) * K + schunk * 8;
  const long rK64 = (long)K * 64;              // 64-row stride (chunk perm repeats mod 8)
  ushort_t* lA = &As[0][0] + tid * 8;
  ushort_t* lB = &Bs[0][0] + tid * 8;

  auto STAGE_LO = [&](int buf, int kt) {  // tile rows 0..127 of A and B
    const ushort_t* ga = gA + (long)kt * 64;
    const ushort_t* gb = gB + (long)kt * 64;
    ushort_t* la = lA + buf * (256 * 64);
    ushort_t* lb = lB + buf * (256 * 64);
    load_lds16(ga,        la);
    load_lds16(ga + rK64, la + 4096);
    load_lds16(gb,        lb);
    load_lds16(gb + rK64, lb + 4096);
  };
  auto STAGE_HI = [&](int buf, int kt) {  // tile rows 128..255
    const ushort_t* ga = gA + (long)kt * 64 + 2 * rK64;
    const ushort_t* gb = gB + (long)kt * 64 + 2 * rK64;
    ushort_t* la = lA + buf * (256 * 64);
    ushort_t* lb = lB + buf * (256 * 64);
    load_lds16(ga,        la + 8192);
    load_lds16(ga + rK64, la + 12288);
    load_lds16(gb,        lb + 8192);
    load_lds16(gb + rK64, lb + 12288);
  };

  // fragment reads: elem = row*64 + (chunk ^ (row&7))*8 ; row&7 == l16&7
  const int arow0 = (wr * 128 + l16) * 64;
  const int brow0 = (wc * 64 + l16) * 64;
  const int cx0 = ((quad)     ^ (l16 & 7)) << 3;  // kstep 0 chunk = quad
  const int cx1 = ((quad + 4) ^ (l16 & 7)) << 3;  // kstep 1 chunk = 4+quad

  floatx4 acc[8][4];
#pragma unroll
  for (int i = 0; i < 8; ++i)
#pragma unroll
    for (int j = 0; j < 4; ++j) acc[i][j] = (floatx4)0.0f;

  const int nk = K >> 6;

  // prologue: tile0 fully + LO(tile1); wait tile0 landed, LO(1) stays in flight
  STAGE_LO(0, 0);
  STAGE_HI(0, 0);
  if (nk > 1) {
    STAGE_LO(1, 1);
    WAIT_VM(4);
  } else {
    WAIT_VM(0);
  }
  BARRIER();

  short8 af[4][2], bf[4][2];

  for (int k = 0; k < nk; ++k) {
    const int cur = k & 1;
    const int nxt = cur ^ 1;
    const ushort_t* Ac = &As[cur][0];
    const ushort_t* Bc = &Bs[cur][0];

    // ---------------- P0: ds A rows0-3 + B cols0-1; stage HI(k+1) ----------
    if (k + 1 < nk) STAGE_HI(nxt, k + 1);
#pragma unroll
    for (int i = 0; i < 4; ++i) {
      af[i][0] = *(const short8*)(Ac + arow0 + i * 1024 + cx0);
      af[i][1] = *(const short8*)(Ac + arow0 + i * 1024 + cx1);
    }
#pragma unroll
    for (int j = 0; j < 2; ++j) {
      bf[j][0] = *(const short8*)(Bc + brow0 + j * 1024 + cx0);
      bf[j][1] = *(const short8*)(Bc + brow0 + j * 1024 + cx1);
    }
    BARRIER();
    WAIT_LGKM0();
    __builtin_amdgcn_s_setprio(1);
#pragma unroll
    for (int i = 0; i < 4; ++i)
#pragma unroll
      for (int j = 0; j < 2; ++j) {
        acc[i][j] = __builtin_amdgcn_mfma_f32_16x16x32_bf16(af[i][0], bf[j][0], acc[i][j], 0, 0, 0);
        acc[i][j] = __builtin_amdgcn_mfma_f32_16x16x32_bf16(af[i][1], bf[j][1], acc[i][j], 0, 0, 0);
      }
    __builtin_amdgcn_s_setprio(0);
    BARRIER();

    // ---------------- P1: ds B cols2-3 ------------------------------------
#pragma unroll
    for (int j = 0; j < 2; ++j) {
      bf[2 + j][0] = *(const short8*)(Bc + brow0 + (2 + j) * 1024 + cx0);
      bf[2 + j][1] = *(const short8*)(Bc + brow0 + (2 + j) * 1024 + cx1);
    }
    BARRIER();
    WAIT_LGKM0();
    __builtin_amdgcn_s_setprio(1);
#pragma unroll
    for (int i = 0; i < 4; ++i)
#pragma unroll
      for (int j = 0; j < 2; ++j) {
        acc[i][2 + j] = __builtin_amdgcn_mfma_f32_16x16x32_bf16(af[i][0], bf[2 + j][0], acc[i][2 + j], 0, 0, 0);
        acc[i][2 + j] = __builtin_amdgcn_mfma_f32_16x16x32_bf16(af[i][1], bf[2 + j][1], acc[i][2 + j], 0, 0, 0);
      }
    __builtin_amdgcn_s_setprio(0);
    BARRIER();

    // ---------------- P2: ds A rows4-7 ------------------------------------
#pragma unroll
    for (int i = 0; i < 4; ++i) {
      af[i][0] = *(const short8*)(Ac + arow0 + (4 + i) * 1024 + cx0);
      af[i][1] = *(const short8*)(Ac + arow0 + (4 + i) * 1024 + cx1);
    }
    BARRIER();
    WAIT_LGKM0();
    __builtin_amdgcn_s_setprio(1);
#pragma unroll
    for (int i = 0; i < 4; ++i)
#pragma unroll
      for (int j = 0; j < 2; ++j) {
        acc[4 + i][2 + j] = __builtin_amdgcn_mfma_f32_16x16x32_bf16(af[i][0], bf[2 + j][0], acc[4 + i][2 + j], 0, 0, 0);
        acc[4 + i][2 + j] = __builtin_amdgcn_mfma_f32_16x16x32_bf16(af[i][1], bf[2 + j][1], acc[4 + i][2 + j], 0, 0, 0);
      }
    __builtin_amdgcn_s_setprio(0);
    BARRIER();

    // ---------------- P3: stage LO(k+2) | MFMA q3 | counted vmcnt ----------
    if (k + 2 < nk) {
      STAGE_LO(cur, k + 2);  // buf cur's last reads finished at P2's barrier
      __builtin_amdgcn_s_setprio(1);
#pragma unroll
      for (int i = 0; i < 4; ++i)
#pragma unroll
        for (int j = 0; j < 2; ++j) {
          acc[4 + i][j] = __builtin_amdgcn_mfma_f32_16x16x32_bf16(af[i][0], bf[j][0], acc[4 + i][j], 0, 0, 0);
          acc[4 + i][j] = __builtin_amdgcn_mfma_f32_16x16x32_bf16(af[i][1], bf[j][1], acc[4 + i][j], 0, 0, 0);
        }
      __builtin_amdgcn_s_setprio(0);
      WAIT_VM(4);  // tile k+1 landed; LO(k+2)'s 4 stay in flight
    } else {
      __builtin_amdgcn_s_setprio(1);
#pragma unroll
      for (int i = 0; i < 4; ++i)
#pragma unroll
        for (int j = 0; j < 2; ++j) {
          acc[4 + i][j] = __builtin_amdgcn_mfma_f32_16x16x32_bf16(af[i][0], bf[j][0], acc[4 + i][j], 0, 0, 0);
          acc[4 + i][j] = __builtin_amdgcn_mfma_f32_16x16x32_bf16(af[i][1], bf[j][1], acc[4 + i][j], 0, 0, 0);
        }
      __builtin_amdgcn_s_setprio(0);
      WAIT_VM(0);  // pipeline drain on last iter
    }
    BARRIER();
  }

  // epilogue: C/D layout col = l16, row = quad*4 + r
  const long rowbase = (long)bm * 256 + wr * 128 + quad * 4;
  const int  colbase = bn * 256 + wc * 64 + l16;
#pragma unroll
  for (int j = 0; j < 4; ++j) {
    const int col = colbase + j * 16;
    const float bv = bias[col];
#pragma unroll
    for (int i = 0; i < 8; ++i) {
      const long row0 = rowbase + i * 16;
#pragma unroll
      for (int r = 0; r < 4; ++r) {
        float v = acc[i][j][r] + bv;
        if (MODE == 0) {
          v = v > 0.0f ? v : 0.0f;
          ((ushort_t*)Cv)[(row0 + r) * N + col] = f2bf(v);
        } else {
          ((float*)Cv)[(row0 + r) * N + col] = v;
        }
      }
    }
  }
}

extern "C" void kernel_launch(void* const* d_in, const int* in_sizes, int n_in,
                              void* d_out, int out_size, void* d_ws, size_t ws_size,
                              hipStream_t stream) {
  const float* h        = (const float*)d_in[0];
  const int*   span_idx = (const int*)d_in[1];
  const float* W1       = (const float*)d_in[2];
  const float* b1       = (const float*)d_in[3];
  const float* W2       = (const float*)d_in[4];
  const float* b2       = (const float*)d_in[5];
  float* out = (float*)d_out;

  // workspace layout (bf16 elements): A | W1T | W2T | Hmid
  ushort_t* A   = (ushort_t*)d_ws;
  ushort_t* W1T = A + (size_t)M_DIM * D_DIM;
  ushort_t* W2T = W1T + (size_t)DFF_DIM * D_DIM;
  ushort_t* Hm  = W2T + (size_t)D_DIM * DFF_DIM;

  // fused prep: both weight transposes + span gather in one launch
  prep<<<2304 + 2304 + M_DIM / 4, 256, 0, stream>>>(W1, W1T, W2, W2T, h, span_idx, A);

  // GEMM1: A (M x D) * W1 (D x DFF) + b1, relu -> Hmid bf16 (M x DFF)
  // 1-D grid + in-kernel XCD swizzle (64 bm-tiles x 12 bn-tiles)
  gemm256<0><<<dim3((M_DIM / 256) * (DFF_DIM / 256)), 512, 0, stream>>>(
      A, W1T, b1, Hm, M_DIM, DFF_DIM, D_DIM);

  // GEMM2: Hmid (M x DFF) * W2 (DFF x D) + b2 -> out fp32 (M x D)
  gemm256<1><<<dim3((M_DIM / 256) * (D_DIM / 256)), 512, 0, stream>>>(
      Hm, W2T, b2, out, M_DIM, D_DIM, DFF_DIM);
}